// Round 2
// 680.466 us; speedup vs baseline: 1.0665x; 1.0665x over previous
//
#include <hip/hip_runtime.h>
#include <hip/hip_fp16.h>
#include <math.h>

#define GRID_R 128
#define DATA_DIM 28
#define PAD_DIM 32
#define NSEG 8
#define SEG_STEPS 32
#define STEP_SIZE 0.001f
#define BG 1.0f

// packed half2 for v_dot2
typedef _Float16 h2f __attribute__((ext_vector_type(2)));

// D = a.x*b.x + a.y*b.y + c (f16 products, f32 accumulate) — one VOP3P instr.
#if __has_builtin(__builtin_amdgcn_fdot2)
__device__ __forceinline__ float fdot2(h2f a, h2f b, float c) {
    return __builtin_amdgcn_fdot2(a, b, c, false);
}
#else
__device__ __forceinline__ float fdot2(h2f a, h2f b, float c) {
    // scalar fallback: still exact-equivalent math, just more instructions
    return fmaf((float)a.x, (float)b.x, fmaf((float)a.y, (float)b.y, c));
}
#endif

#if __has_builtin(__builtin_amdgcn_exp2f)
__device__ __forceinline__ float fexp2(float x)    { return __builtin_amdgcn_exp2f(x); }
__device__ __forceinline__ float fexp2neg(float x) { return __builtin_amdgcn_exp2f(-x); }
#else
__device__ __forceinline__ float fexp2(float x) {
    float r; asm("v_exp_f32 %0, %1" : "=v"(r) : "v"(x)); return r;
}
__device__ __forceinline__ float fexp2neg(float x) {
    float r; asm("v_exp_f32 %0, -%1" : "=v"(r) : "v"(x)); return r;
}
#endif

#if __has_builtin(__builtin_amdgcn_rcpf)
__device__ __forceinline__ float frcp(float x) { return __builtin_amdgcn_rcpf(x); }
#else
__device__ __forceinline__ float frcp(float x) {
    float r; asm("v_rcp_f32 %0, %1" : "=v"(r) : "v"(x)); return r;
}
#endif

// ---------------------------------------------------------------------------
// Shared per-step geometry. Used by BOTH geom and march paths so the
// t-sequence is bit-identical. The t-arithmetic is UNCHANGED from the
// verified 726us kernel (voxel picks at cell boundaries are rounding-
// sensitive). flat via exact float fma: fx*16384+fy*128+fz < 2^21 is exactly
// representable, so the (int) of the fma chain == old int mad chain.
// ---------------------------------------------------------------------------
__device__ __forceinline__ float march_step(
    float t, float ox, float oy, float oz,
    float dx, float dy, float dz,
    float idx, float idy, float idz, int* flat)
{
    float px = (ox + t*dx) * 128.0f;
    float py = (oy + t*dy) * 128.0f;
    float pz = (oz + t*dz) * 128.0f;
    float fx = fminf(fmaxf(floorf(px), 0.0f), 127.0f);
    float fy = fminf(fmaxf(floorf(py), 0.0f), 127.0f);
    float fz = fminf(fmaxf(floorf(pz), 0.0f), 127.0f);
    float ff = fmaf(fx, 16384.0f, fmaf(fy, 128.0f, fz));   // exact, < 2^21
    *flat = (int)ff;
    float cx = px - fx, cy = py - fy, cz = pz - fz;
    float a1x = -cx*idx, a1y = -cy*idy, a1z = -cz*idz;
    float a2x = a1x+idx, a2y = a1y+idy, a2z = a1z+idz;
    float e1 = fminf(fminf(fmaxf(a1x,a2x), fmaxf(a1y,a2y)), fmaxf(a1z,a2z));
    e1 = fminf(e1, 1e9f);
    return e1 * (1.0f/128.0f) + STEP_SIZE;
}

// common ray setup (unchanged)
#define RAY_SETUP(i)                                                          \
    float ox = origins[3*(i)+0], oy = origins[3*(i)+1], oz = origins[3*(i)+2];\
    float dx = dirs_in[3*(i)+0], dy = dirs_in[3*(i)+1], dz = dirs_in[3*(i)+2];\
    float dn = sqrtf(dx*dx + dy*dy + dz*dz);                                  \
    float rdn = 1.0f / dn;                                                    \
    dx *= rdn; dy *= rdn; dz *= rdn;                                          \
    float idx = 1.0f / (dx + 1e-9f);                                          \
    float idy = 1.0f / (dy + 1e-9f);                                          \
    float idz = 1.0f / (dz + 1e-9f);                                          \
    float t1x = -ox*idx, t1y = -oy*idy, t1z = -oz*idz;                        \
    float t2x = t1x+idx, t2y = t1y+idy, t2z = t1z+idz;                        \
    float t0   = fmaxf(fmaxf(fmaxf(fminf(t1x,t2x), fminf(t1y,t2y)), fminf(t1z,t2z)), 0.0f); \
    float tmax = fminf(fminf(fminf(fmaxf(t1x,t2x), fmaxf(t1y,t2y)), fmaxf(t1z,t2z)), 1e9f);

// ---------------------------------------------------------------------------
// Fused pre-pass: geom (blocks [0, nGeomB)) + fp32->fp16 grid convert
// (remaining blocks). Independent work; fusing overlaps VALU-bound geom with
// memory-bound convert instead of serializing two dispatches.
//
// CHANNEL-MAJOR voxel record (32 halfs = 64 B), s[] = half index:
//   s[ 0.. 8] = ch0 f0..f8,  s[9]  = pad
//   s[10..17] = ch1 f9..f16, s[18] = f17, s[19] = pad
//   s[20..28] = ch2 f18..f26, s[29] = pad
//   s[30]     = sigma (f27),  s[31] = pad
// Each channel = 5 aligned half2 pairs -> 5 x v_dot2_f32_f16 per channel.
// ---------------------------------------------------------------------------
__global__ __launch_bounds__(256) void prep_kernel(
    const float* __restrict__ tree, __half* __restrict__ vox, int nvox,
    const float* __restrict__ origins, const float* __restrict__ dirs_in,
    float* __restrict__ ckpt, int nB, int nGeomB)
{
    if ((int)blockIdx.x < nGeomB) {
        // ---- geometry checkpoints (one thread per ray, no gathers) ----
        int i = blockIdx.x * 256 + threadIdx.x;
        if (i >= nB) return;
        RAY_SETUP(i);
        float ck[NSEG];
        float t = t0;
        ck[0] = t0;
#pragma unroll
        for (int k = 1; k < NSEG; ++k) {
            if (t < tmax) {
                for (int j = 0; j < SEG_STEPS; ++j) {
                    int fl;
                    t += march_step(t, ox, oy, oz, dx, dy, dz, idx, idy, idz, &fl);
                    if (t >= tmax) break;
                }
            }
            ck[k] = t;
        }
        float* cp = ckpt + (size_t)i * NSEG;
        *(float4*)(cp + 0) = make_float4(ck[0], ck[1], ck[2], ck[3]);
        *(float4*)(cp + 4) = make_float4(ck[4], ck[5], ck[6], ck[7]);
    } else {
        // ---- fp32 -> fp16 convert + channel-major reorder, 1 thread/voxel ----
        int v = (blockIdx.x - nGeomB) * 256 + threadIdx.x;
        if (v >= nvox) return;
        const float4* s4 = (const float4*)(tree + (size_t)v * DATA_DIM); // 112B, 16B-aligned
        float4 A  = s4[0], B4 = s4[1], C4 = s4[2], D4 = s4[3],
               E4 = s4[4], F4 = s4[5], G4 = s4[6];
        uint4* d = (uint4*)(vox + (size_t)v * PAD_DIM);
        union Q { __half2 h[4]; uint4 u; } q;
        q.h[0] = __floats2half2_rn(A.x,  A.y);   // f0 f1
        q.h[1] = __floats2half2_rn(A.z,  A.w);   // f2 f3
        q.h[2] = __floats2half2_rn(B4.x, B4.y);  // f4 f5
        q.h[3] = __floats2half2_rn(B4.z, B4.w);  // f6 f7
        d[0] = q.u;
        q.h[0] = __floats2half2_rn(C4.x, 0.f);   // f8 pad   (end ch0)
        q.h[1] = __floats2half2_rn(C4.y, C4.z);  // f9 f10
        q.h[2] = __floats2half2_rn(C4.w, D4.x);  // f11 f12
        q.h[3] = __floats2half2_rn(D4.y, D4.z);  // f13 f14
        d[1] = q.u;
        q.h[0] = __floats2half2_rn(D4.w, E4.x);  // f15 f16
        q.h[1] = __floats2half2_rn(E4.y, 0.f);   // f17 pad  (end ch1)
        q.h[2] = __floats2half2_rn(E4.z, E4.w);  // f18 f19
        q.h[3] = __floats2half2_rn(F4.x, F4.y);  // f20 f21
        d[2] = q.u;
        q.h[0] = __floats2half2_rn(F4.z, F4.w);  // f22 f23
        q.h[1] = __floats2half2_rn(G4.x, G4.y);  // f24 f25
        q.h[2] = __floats2half2_rn(G4.z, 0.f);   // f26 pad  (end ch2)
        q.h[3] = __floats2half2_rn(G4.w, 0.f);   // sigma pad
        d[3] = q.u;
    }
}

// ---------------------------------------------------------------------------
// Main march: 8 threads/ray (one per 32-step segment), combined by 8-lane
// shuffles. SH shading via v_dot2_f32_f16 against fp16 SH coefficients
// pre-scaled by log2(e) (so sigmoid/att use raw v_exp_f32); sigmoid divide
// via v_rcp_f32. ~118 -> ~77 VALU ops per step. Geometry bit-identical to
// the verified kernel.
// ---------------------------------------------------------------------------
__global__ __launch_bounds__(256, 8) void march_kernel(
    const __half* __restrict__ vox_grid,
    const float* __restrict__ origins,
    const float* __restrict__ dirs_in,
    const float* __restrict__ viewdirs,
    const float* __restrict__ invradius,
    const float* __restrict__ ckpt,
    float* __restrict__ out, int nB)
{
    int tid = blockIdx.x * blockDim.x + threadIdx.x;
    int ray = tid >> 3;
    int seg = tid & 7;
    if (ray >= nB) return;

    RAY_SETUP(ray);

    float vx = viewdirs[3*ray+0], vy = viewdirs[3*ray+1], vz = viewdirs[3*ray+2];
    float irx = invradius[0], iry = invradius[1], irz = invradius[2];
    float qx = dx / irx, qy = dy / iry, qz = dz / irz;
    float delta_scale = sqrtf(qx*qx + qy*qy + qz*qz);

    const float C1 = 0.4886025119029199f;
    const float L2E = 1.4426950408889634f;   // log2(e), folded into SH + att
    float sh0 = 0.28209479177387814f;
    float sh1 = -C1 * vy;
    float sh2 =  C1 * vz;
    float sh3 = -C1 * vx;
    float sh4 =  1.0925484305920792f  * vx * vy;
    float sh5 = -1.0925484305920792f * vy * vz;
    float sh6 =  0.31539156525252005f * (2.0f*vz*vz - vx*vx - vy*vy);
    float sh7 = -1.0925484305920792f * vx * vz;
    float sh8 =  0.5462742152960396f  * (vx*vx - vy*vy);

    // loop-invariant fp16 coefficient pairs (pre-scaled by log2 e)
    h2f S01 = { (_Float16)(sh0*L2E), (_Float16)(sh1*L2E) };
    h2f S23 = { (_Float16)(sh2*L2E), (_Float16)(sh3*L2E) };
    h2f S45 = { (_Float16)(sh4*L2E), (_Float16)(sh5*L2E) };
    h2f S67 = { (_Float16)(sh6*L2E), (_Float16)(sh7*L2E) };
    h2f S8z = { (_Float16)(sh8*L2E), (_Float16)0.0f      };
    float nds = -delta_scale * L2E;          // att = 2^(dt*sigma*nds)

    float t = ckpt[(size_t)ray * NSEG + seg];
    float light = 1.0f;                      // segment-local transmittance
    float o0 = 0.f, o1 = 0.f, o2 = 0.f;

    for (int j = 0; j < SEG_STEPS; ++j) {
        if (t >= tmax) break;
        int flat;
        float dt = march_step(t, ox, oy, oz, dx, dy, dz, idx, idy, idz, &flat);

        const uint4* vp = (const uint4*)(vox_grid + (size_t)flat * PAD_DIM);
        union { uint4 u[4]; h2f h[16]; _Float16 s[32]; } rec;
        rec.u[0] = vp[0]; rec.u[1] = vp[1]; rec.u[2] = vp[2]; rec.u[3] = vp[3];

        float sigma = fmaxf((float)rec.s[30], 0.0f);
        float att = fexp2(dt * sigma * nds);
        float la  = light * att;             // light AFTER this step
        float w   = light - la;              // = light*(1-att)
        light = la;

        // r_c already scaled by log2(e): sigmoid = rcp(1 + 2^-r)
        float r0 = fdot2(rec.h[ 4], S8z, fdot2(rec.h[ 3], S67, fdot2(rec.h[ 2], S45,
                   fdot2(rec.h[ 1], S23, fdot2(rec.h[ 0], S01, 0.0f)))));
        float r1 = fdot2(rec.h[ 9], S8z, fdot2(rec.h[ 8], S67, fdot2(rec.h[ 7], S45,
                   fdot2(rec.h[ 6], S23, fdot2(rec.h[ 5], S01, 0.0f)))));
        float r2 = fdot2(rec.h[14], S8z, fdot2(rec.h[13], S67, fdot2(rec.h[12], S45,
                   fdot2(rec.h[11], S23, fdot2(rec.h[10], S01, 0.0f)))));

        float g0 = frcp(1.0f + fexp2neg(r0));
        float g1 = frcp(1.0f + fexp2neg(r1));
        float g2 = frcp(1.0f + fexp2neg(r2));

        o0 = fmaf(w, g0, o0);
        o1 = fmaf(w, g1, o1);
        o2 = fmaf(w, g2, o2);

        t += dt;
    }

    // ---- 8-lane combine (lanes 8m..8m+7 hold segments 0..7 of one ray) ----
    float l0 = __shfl(light, 0, 8);
    float l1 = __shfl(light, 1, 8);
    float l2 = __shfl(light, 2, 8);
    float l3 = __shfl(light, 3, 8);
    float l4 = __shfl(light, 4, 8);
    float l5 = __shfl(light, 5, 8);
    float l6 = __shfl(light, 6, 8);
    float l7 = __shfl(light, 7, 8);

    float P = 1.0f;
    if (seg > 0) P *= l0;
    if (seg > 1) P *= l1;
    if (seg > 2) P *= l2;
    if (seg > 3) P *= l3;
    if (seg > 4) P *= l4;
    if (seg > 5) P *= l5;
    if (seg > 6) P *= l6;
    float total_light = l0*l1*l2*l3*l4*l5*l6*l7;

    o0 *= P; o1 *= P; o2 *= P;
    o0 += __shfl_xor(o0, 1, 8); o0 += __shfl_xor(o0, 2, 8); o0 += __shfl_xor(o0, 4, 8);
    o1 += __shfl_xor(o1, 1, 8); o1 += __shfl_xor(o1, 2, 8); o1 += __shfl_xor(o1, 4, 8);
    o2 += __shfl_xor(o2, 1, 8); o2 += __shfl_xor(o2, 2, 8); o2 += __shfl_xor(o2, 4, 8);

    if (seg == 0) {
        out[3*ray+0] = o0 + total_light * BG;
        out[3*ray+1] = o1 + total_light * BG;
        out[3*ray+2] = o2 + total_light * BG;
    }
}

extern "C" void kernel_launch(void* const* d_in, const int* in_sizes, int n_in,
                              void* d_out, int out_size, void* d_ws, size_t ws_size,
                              hipStream_t stream) {
    const float* tree      = (const float*)d_in[0];
    const float* origins   = (const float*)d_in[1];
    const float* dirs      = (const float*)d_in[2];
    const float* viewdirs  = (const float*)d_in[3];
    const float* invradius = (const float*)d_in[4];
    float* out = (float*)d_out;

    int nB   = in_sizes[1] / 3;
    int nvox = in_sizes[0] / DATA_DIM;

    const int block = 256;
    __half* hgrid = (__half*)d_ws;
    float* ckpt = (float*)((char*)d_ws + (size_t)nvox * PAD_DIM * sizeof(__half));

    int nGeomB = (nB + block - 1) / block;
    int nConvB = (nvox + block - 1) / block;
    prep_kernel<<<nGeomB + nConvB, block, 0, stream>>>(
        tree, hgrid, nvox, origins, dirs, ckpt, nB, nGeomB);

    int nmarch = nB * NSEG;
    march_kernel<<<(nmarch + block - 1) / block, block, 0, stream>>>(
        hgrid, origins, dirs, viewdirs, invradius, ckpt, out, nB);
    (void)ws_size;
}